// Round 7
// baseline (587.110 us; speedup 1.0000x reference)
//
#include <hip/hip_runtime.h>
#include <hip/hip_bf16.h>

// N=65536 points, H=256, 4 hidden layers, ReLU MLP -> (psi,p).
// ReLU => piecewise linear => Hessians vanish; f = p_x, g = p_y (RHO=1).
// Pipeline:
//   1) fp32 forward replicating np/BLAS arithmetic BIT-EXACTLY (v20/v11
//      verbatim, ~400us). Weight-supply ceiling is STRUCTURAL at ~68% VALU
//      duty: s_load 399us >> LDS-broadcast (spill, 5163us) > VMEM-broadcast
//      (latency, 1037us); drain-stagger null -> fwd declared done.
//   2) tangent kernel v25: whole-layer B in REGISTERS. v19 was LDS-pipe
//      bound (~21k cyc/block of b128 ops; 2/3 = Bpan round-trip). v24
//      (B-direct, load-at-use) exposed L2 latency per k-step (170us).
//      v25 loads all 32 B fragments (128 VGPR) at layer top -> compiler's
//      natural early-issue + counted vmcnt; latency hidden under af+MFMA
//      of earlier slices; LDS ops drop 3x. launch_bounds(256,2): 256-VGPR
//      cap, 2 blocks/CU (LDS 38.9KB). breg fully statically indexed ->
//      registers, no scratch. Same f16 bits, same MFMA products, same
//      s-ascending order -> BIT-IDENTICAL output (absmax 6.103516e-05).
// Workspace: masks 5x2MB | Wt 512KB

#define NPTS 65536
#define HDIM 256

typedef _Float16 half8_t __attribute__((ext_vector_type(8)));
typedef _Float16 half4_t __attribute__((ext_vector_type(4)));
typedef float floatx4 __attribute__((ext_vector_type(4)));

// ---------------------------------------------------------------- fused fp32 forward (np/BLAS-exact) — v11/v20 verbatim
__global__ void __launch_bounds__(1024) fwd_fused_kernel(
    const float* __restrict__ x, const float* __restrict__ y, const float* __restrict__ t,
    const float* __restrict__ Win, const float* __restrict__ b_in,
    const float* __restrict__ Wh, const float* __restrict__ b_h,
    const float* __restrict__ Wout, const float* __restrict__ b_out,
    unsigned char* __restrict__ masks, float* __restrict__ out) {
  constexpr int SH = 257;              // odd stride: conflict-free b32
  __shared__ float hT[128 * SH];       // [pt][k]  131584 B
  __shared__ float pscr[16][132];      // wave partials for p (8448 B)

  const int tid = threadIdx.x;
  const int lane = tid & 63;
  const int w = __builtin_amdgcn_readfirstlane(tid >> 6);       // wave id 0..15
  const int c0 = w * 16;                                        // 16-col group
  const int p0 = blockIdx.x * 128;
  const int pA = p0 + lane;            // point A
  const int pB = p0 + 64 + lane;       // point B

  // ---- layer 1: dot = z @ Win (k ascending: x,y,t), then + b_in  [bit-exact]
  {
    float xa = x[pA], ya = y[pA], ta = t[pA];
    float xb = x[pB], yb = y[pB], tb = t[pB];
    unsigned ma = 0, mb = 0;
#pragma unroll
    for (int e = 0; e < 16; ++e) {
      int c = c0 + e;                  // uniform -> Win reads are scalar
      float w0 = Win[c], w1 = Win[256 + c], w2 = Win[512 + c], bb = b_in[c];
      float da = fmaf(xa, w0, 0.f);
      da = fmaf(ya, w1, da);
      da = fmaf(ta, w2, da);
      float aa = da + bb;
      bool posa = aa > 0.f;
      hT[lane * SH + c] = posa ? aa : 0.f;
      ma |= (posa ? 1u : 0u) << e;
      float db = fmaf(xb, w0, 0.f);
      db = fmaf(yb, w1, db);
      db = fmaf(tb, w2, db);
      float ab = db + bb;
      bool posb = ab > 0.f;
      hT[(64 + lane) * SH + c] = posb ? ab : 0.f;
      mb |= (posb ? 1u : 0u) << e;
    }
    *(unsigned short*)(masks + (size_t)pA * 32 + w * 2) = (unsigned short)ma;
    *(unsigned short*)(masks + (size_t)pB * 32 + w * 2) = (unsigned short)mb;
  }
  __syncthreads();

  // ---- hidden layers: single fp32 accumulator per element, k ascending, fmaf
  for (int l = 0; l < 4; ++l) {
    const float* Wl = Wh + (size_t)l * 65536 + c0;   // + uniform col offset
    float accA[16] = {};
    float accB[16] = {};
#pragma unroll 2
    for (int k = 0; k < 256; ++k) {
      float hA = hT[lane * SH + k];          // per-lane LDS, conflict-free
      float hB = hT[(64 + lane) * SH + k];
      const float* wr = Wl + k * 256;        // wave-uniform -> s_load_dwordx16
#pragma unroll
      for (int e = 0; e < 16; ++e) {
        float wv = wr[e];
        accA[e] = fmaf(hA, wv, accA[e]);
        accB[e] = fmaf(hB, wv, accB[e]);
      }
    }
    __syncthreads();                   // all hT reads done before overwrite
    unsigned ma = 0, mb = 0;
    float hnA[16], hnB[16];
#pragma unroll
    for (int e = 0; e < 16; ++e) {
      float bb = b_h[l * 256 + c0 + e];
      float aa = accA[e] + bb;
      bool posa = aa > 0.f;
      hnA[e] = posa ? aa : 0.f;
      ma |= (posa ? 1u : 0u) << e;
      float ab = accB[e] + bb;
      bool posb = ab > 0.f;
      hnB[e] = posb ? ab : 0.f;
      mb |= (posb ? 1u : 0u) << e;
    }
    *(unsigned short*)(masks + ((size_t)(l + 1) * NPTS + pA) * 32 + w * 2) =
        (unsigned short)ma;
    *(unsigned short*)(masks + ((size_t)(l + 1) * NPTS + pB) * 32 + w * 2) =
        (unsigned short)mb;
#pragma unroll
    for (int e = 0; e < 16; ++e) {
      hT[lane * SH + c0 + e] = hnA[e];
      hT[(64 + lane) * SH + c0 + e] = hnB[e];
    }
    __syncthreads();
  }

  // ---- p = h5 . Wout[:,1] + b_out[1]
  {
    float sA = 0.f, sB = 0.f;
#pragma unroll
    for (int e = 0; e < 16; ++e) {
      float wv = Wout[2 * (c0 + e) + 1];
      sA = fmaf(hT[lane * SH + c0 + e], wv, sA);
      sB = fmaf(hT[(64 + lane) * SH + c0 + e], wv, sB);
    }
    pscr[w][lane] = sA;
    pscr[w][64 + lane] = sB;
  }
  __syncthreads();
  if (tid < 128) {
    float s2 = 0.f;
#pragma unroll
    for (int g = 0; g < 16; ++g) s2 += pscr[g][tid];
    out[2 * NPTS + p0 + tid] = s2 + b_out[1];
  }
}

// ---------------------------------------------------------------- prep: Wh fp32 [l][k][n] -> f16 [l][n][k]
__global__ void __launch_bounds__(256) prep_weights_kernel(
    const float* __restrict__ Wh, _Float16* __restrict__ Wt) {
  int i = blockIdx.x * 256 + threadIdx.x;   // 0..262143
  int l = i >> 16;
  int rem = i & 65535;
  int k = rem >> 8, n = rem & 255;
  Wt[(size_t)(l << 16) + n * 256 + k] = (_Float16)Wh[i];
}

// ---------------------------------------------------------------- fused tangent chain (init + 4 layers + finalize)
// Block: 256 thr = 4 waves. 32 points -> 64 rows (0..31 x-tangent, 32..63 y).
// Tile M=64 x N=256; wave wn owns 64 rows x 64 cols. T lives in Apan (f16).
// v25: B for the WHOLE layer lives in registers (breg[8][4], 128 VGPR),
// loaded at layer top from L2-resident Wt ([l][n][k]: fragment = 8
// contiguous halves = 1 global_load_dwordx4). No Bpan. LDS = 38.9KB.
// mfma(bf, af, acc) OPERAND SWAP -> D[row = n-local quad*4+reg]
// [col = m-local l15]: lane holds 4 consecutive n for one row m ->
// write-back is 16 ds_write_b64. Finalize = one MFMA chain per wave.
// mfma_f32_16x16x32_f16: A[m=lane&15][k=quad*8+j], B[k=quad*8+j][n=lane&15],
//                        D[row=quad*4+reg][col=lane&15]  (verified layouts)
__global__ void __launch_bounds__(256, 2) tangent_fused_kernel(
    const float* __restrict__ Win,
    const _Float16* __restrict__ Wt,          // [l][n][k] (pre-transposed)
    const unsigned int* __restrict__ maskDw,  // [5][NPTS][8] dwords
    const float* __restrict__ Wout, float* __restrict__ out) {
  constexpr int SA = 264;   // A row stride (halves): 256 + 8 pad
  __shared__ alignas(16) _Float16 Apan[64 * SA];        // 33792 B
  __shared__ unsigned int smask[5 * 256];               // 5120 B

  const int tid = threadIdx.x;
  const int lane = tid & 63;
  const int wn = tid >> 6;          // wave = 64-col group
  const int l15 = lane & 15, quad = lane >> 4;
  const int p0 = blockIdx.x * 32;   // 32 points per block

  // ---- stage all 5 mask layers (32 pts x 8 dw each)
#pragma unroll
  for (int i = 0; i < 5; ++i)
    smask[i * 256 + tid] = maskDw[(size_t)i * NPTS * 8 + (size_t)p0 * 8 + tid];
  __syncthreads();

  // ---- init T1 into Apan: row<32 -> x-tangent (Win row 0), row>=32 -> y (row 1)
#pragma unroll
  for (int i = 0; i < 8; ++i) {
    int g = tid + 256 * i;          // 0..2047 col-groups of 8
    int row = g >> 5, cg = g & 31;
    int c0 = cg * 8, pt = row & 31, tg = row >> 5;
    unsigned dw = smask[pt * 8 + (c0 >> 5)];
    half8_t v;
#pragma unroll
    for (int e = 0; e < 8; ++e) {
      bool m = (dw >> ((cg & 3) * 8 + e)) & 1;
      v[e] = m ? (_Float16)Win[tg * 256 + c0 + e] : (_Float16)0.f;
    }
    *(half8_t*)&Apan[row * SA + c0] = v;
  }
  __syncthreads();                  // Apan init visible to all waves

  // ---- 4 layers: acc = A @ W_l (computed transposed), gate, back into Apan
  for (int l = 0; l < 4; ++l) {
    const _Float16* Bw = Wt + (size_t)l * 65536 + (size_t)(wn * 64) * 256;

    // ---- load ALL B fragments for this layer into registers (32 x b128).
    // Program-order early, consumed far below -> compiler issues early and
    // counts vmcnt down slice-by-slice; latency hides under af+MFMA.
    // slice s (k = s*32 + quad*8), frag nj (rows nj*16+l15).
    half8_t breg[8][4];
#pragma unroll
    for (int s = 0; s < 8; ++s)
#pragma unroll
      for (int nj = 0; nj < 4; ++nj)
        breg[s][nj] = *(const half8_t*)(Bw + (size_t)(nj * 16 + l15) * 256 +
                                        s * 32 + quad * 8);

    floatx4 acc[4][4] = {};   // [mi][nj], element = D[n-local][m-local]
#pragma unroll
    for (int s = 0; s < 8; ++s) {     // s = kp*2+ks of v19: same k order
      half8_t af[4];
#pragma unroll
      for (int mi = 0; mi < 4; ++mi)
        af[mi] = *(const half8_t*)&Apan[(mi * 16 + l15) * SA + s * 32 + quad * 8];
      // SWAPPED operands: same products/order as v19 (bit-identical values),
      // transposed D layout (lane = one T-row m, 4 consecutive n per reg)
#pragma unroll
      for (int mi = 0; mi < 4; ++mi)
#pragma unroll
        for (int nj = 0; nj < 4; ++nj)
          acc[mi][nj] = __builtin_amdgcn_mfma_f32_16x16x32_f16(breg[s][nj], af[mi], acc[mi][nj], 0, 0, 0);
    }
    __syncthreads();          // all Apan reads of this layer done
    // gated write-back: lane (l15,quad) of tile (mi,nj) holds rows m=mi*16+l15,
    // cols C = wn*64 + nj*16 + quad*4 + r  -> one b64 per (mi,nj)
    const unsigned int* ml = &smask[(l + 1) * 256];
    uint2 mA = *(const uint2*)&ml[l15 * 8 + wn * 2];         // pt = l15
    uint2 mB = *(const uint2*)&ml[(16 + l15) * 8 + wn * 2];  // pt = 16+l15
#pragma unroll
    for (int mi = 0; mi < 4; ++mi) {
      uint2 md = (mi & 1) ? mB : mA;
      int m = mi * 16 + l15;
#pragma unroll
      for (int nj = 0; nj < 4; ++nj) {
        unsigned dw = (nj < 2) ? md.x : md.y;
        int bitbase = (nj & 1) * 16 + quad * 4;
        half4_t v;
#pragma unroll
        for (int r = 0; r < 4; ++r)
          v[r] = ((dw >> (bitbase + r)) & 1) ? (_Float16)acc[mi][nj][r]
                                             : (_Float16)0.f;
        *(half4_t*)&Apan[m * SA + wn * 64 + nj * 16 + quad * 4] = v;
      }
    }
    __syncthreads();
  }

  // ---- finalize: T5 @ Wout via one MFMA chain per wave (rows wn*16..+15)
  {
    floatx4 facc = {0.f, 0.f, 0.f, 0.f};
#pragma unroll
    for (int kc = 0; kc < 8; ++kc) {
      half8_t a = *(const half8_t*)&Apan[(wn * 16 + l15) * SA + kc * 32 + quad * 8];
      half8_t b;
#pragma unroll
      for (int j = 0; j < 8; ++j) {
        int k = kc * 32 + quad * 8 + j;
        b[j] = (l15 < 2) ? (_Float16)Wout[2 * k + l15] : (_Float16)0.f;
      }
      facc = __builtin_amdgcn_mfma_f32_16x16x32_f16(a, b, facc, 0, 0, 0);
    }
    // D[row=quad*4+r][col=l15]: global row = wn*16 + quad*4 + r; col 0 -> psi
    // derivative dot (u/v), col 1 -> p derivative dot (f/g)
    if (l15 < 2) {
#pragma unroll
      for (int r = 0; r < 4; ++r) {
        int row = wn * 16 + quad * 4 + r;
        int pt = p0 + (row & 31);
        float val = facc[r];
        if (l15 == 0) {
          if (row < 32) out[NPTS + pt] = -val;      // v = -psi_x
          else          out[pt] = val;              // u =  psi_y
        } else {
          if (row < 32) out[3 * NPTS + pt] = val;   // f = p_x
          else          out[4 * NPTS + pt] = val;   // g = p_y
        }
      }
    }
  }
}

// ---------------------------------------------------------------- launch
extern "C" void kernel_launch(void* const* d_in, const int* in_sizes, int n_in,
                              void* d_out, int out_size, void* d_ws, size_t ws_size,
                              hipStream_t stream) {
  const float* x = (const float*)d_in[0];
  const float* y = (const float*)d_in[1];
  const float* t = (const float*)d_in[2];
  const float* Win = (const float*)d_in[3];
  const float* b_in = (const float*)d_in[4];
  const float* Wh = (const float*)d_in[5];
  const float* b_h = (const float*)d_in[6];
  const float* Wout = (const float*)d_in[7];
  const float* b_out = (const float*)d_in[8];
  float* out = (float*)d_out;

  char* ws = (char*)d_ws;
  constexpr size_t MASK_SZ = (size_t)NPTS * 32;       // 2 MB per layer
  unsigned char* masks = (unsigned char*)ws;
  _Float16* Wt = (_Float16*)(ws + 5 * MASK_SZ);

  // weight transpose/cast first (independent of fwd)
  prep_weights_kernel<<<1024, 256, 0, stream>>>(Wh, Wt);

  // fp32 np-exact forward: masks L0..L4 + p
  fwd_fused_kernel<<<NPTS / 128, 1024, 0, stream>>>(
      x, y, t, Win, b_in, Wh, b_h, Wout, b_out, masks, out);

  // fused tangent chain: init + 4 MFMA layers + finalize (u,v,f,g)
  tangent_fused_kernel<<<NPTS / 32, 256, 0, stream>>>(
      Win, Wt, (const unsigned int*)masks, Wout, out);
}

// Round 8
// 512.472 us; speedup vs baseline: 1.1456x; 1.1456x over previous
//
#include <hip/hip_runtime.h>
#include <hip/hip_bf16.h>

// N=65536 points, H=256, 4 hidden layers, ReLU MLP -> (psi,p).
// ReLU => piecewise linear => Hessians vanish; f = p_x, g = p_y (RHO=1).
// Pipeline:
//   1) fp32 forward replicating np/BLAS arithmetic BIT-EXACTLY (v20/v11
//      verbatim, ~400us). Weight-supply ceiling is STRUCTURAL at ~68% VALU
//      duty (s_load >> LDS-broadcast(spill) > VMEM-broadcast; stagger null).
//   2) tangent kernel v26 = v25 structure + FRAGMENT-MAJOR weight layout.
//      Post-mortem chain: v19 (Bpan round-trip) 120us = LDS-pipe bound;
//      v24/v25 (B direct from [l][n][k]) REGRESSED because the fragment
//      read row=nj*16+l15 is a 16-way scattered gather (16 cache segments
//      per dwordx4 -> ~16x VMEM issue cost). v26: prep emits
//      Wt2[l][wn][s][nj][lane][8] so each B-fragment load is 64 lanes x
//      16B = 1KB CONTIGUOUS (coalescing sweet spot; pre-swizzled-global
//      pattern). All 32 fragments/wave/layer load at layer top into
//      breg[8][4] (128 VGPR, static idx); no Bpan; LDS 38.9KB; no staging
//      writes. Same f16 bits, same MFMA products, same s-order ->
//      BIT-IDENTICAL output (absmax 6.103516e-05).
// Workspace: masks 5x2MB | Wt2 512KB

#define NPTS 65536
#define HDIM 256

typedef _Float16 half8_t __attribute__((ext_vector_type(8)));
typedef _Float16 half4_t __attribute__((ext_vector_type(4)));
typedef float floatx4 __attribute__((ext_vector_type(4)));

// ---------------------------------------------------------------- fused fp32 forward (np/BLAS-exact) — v11/v20 verbatim
__global__ void __launch_bounds__(1024) fwd_fused_kernel(
    const float* __restrict__ x, const float* __restrict__ y, const float* __restrict__ t,
    const float* __restrict__ Win, const float* __restrict__ b_in,
    const float* __restrict__ Wh, const float* __restrict__ b_h,
    const float* __restrict__ Wout, const float* __restrict__ b_out,
    unsigned char* __restrict__ masks, float* __restrict__ out) {
  constexpr int SH = 257;              // odd stride: conflict-free b32
  __shared__ float hT[128 * SH];       // [pt][k]  131584 B
  __shared__ float pscr[16][132];      // wave partials for p (8448 B)

  const int tid = threadIdx.x;
  const int lane = tid & 63;
  const int w = __builtin_amdgcn_readfirstlane(tid >> 6);       // wave id 0..15
  const int c0 = w * 16;                                        // 16-col group
  const int p0 = blockIdx.x * 128;
  const int pA = p0 + lane;            // point A
  const int pB = p0 + 64 + lane;       // point B

  // ---- layer 1: dot = z @ Win (k ascending: x,y,t), then + b_in  [bit-exact]
  {
    float xa = x[pA], ya = y[pA], ta = t[pA];
    float xb = x[pB], yb = y[pB], tb = t[pB];
    unsigned ma = 0, mb = 0;
#pragma unroll
    for (int e = 0; e < 16; ++e) {
      int c = c0 + e;                  // uniform -> Win reads are scalar
      float w0 = Win[c], w1 = Win[256 + c], w2 = Win[512 + c], bb = b_in[c];
      float da = fmaf(xa, w0, 0.f);
      da = fmaf(ya, w1, da);
      da = fmaf(ta, w2, da);
      float aa = da + bb;
      bool posa = aa > 0.f;
      hT[lane * SH + c] = posa ? aa : 0.f;
      ma |= (posa ? 1u : 0u) << e;
      float db = fmaf(xb, w0, 0.f);
      db = fmaf(yb, w1, db);
      db = fmaf(tb, w2, db);
      float ab = db + bb;
      bool posb = ab > 0.f;
      hT[(64 + lane) * SH + c] = posb ? ab : 0.f;
      mb |= (posb ? 1u : 0u) << e;
    }
    *(unsigned short*)(masks + (size_t)pA * 32 + w * 2) = (unsigned short)ma;
    *(unsigned short*)(masks + (size_t)pB * 32 + w * 2) = (unsigned short)mb;
  }
  __syncthreads();

  // ---- hidden layers: single fp32 accumulator per element, k ascending, fmaf
  for (int l = 0; l < 4; ++l) {
    const float* Wl = Wh + (size_t)l * 65536 + c0;   // + uniform col offset
    float accA[16] = {};
    float accB[16] = {};
#pragma unroll 2
    for (int k = 0; k < 256; ++k) {
      float hA = hT[lane * SH + k];          // per-lane LDS, conflict-free
      float hB = hT[(64 + lane) * SH + k];
      const float* wr = Wl + k * 256;        // wave-uniform -> s_load_dwordx16
#pragma unroll
      for (int e = 0; e < 16; ++e) {
        float wv = wr[e];
        accA[e] = fmaf(hA, wv, accA[e]);
        accB[e] = fmaf(hB, wv, accB[e]);
      }
    }
    __syncthreads();                   // all hT reads done before overwrite
    unsigned ma = 0, mb = 0;
    float hnA[16], hnB[16];
#pragma unroll
    for (int e = 0; e < 16; ++e) {
      float bb = b_h[l * 256 + c0 + e];
      float aa = accA[e] + bb;
      bool posa = aa > 0.f;
      hnA[e] = posa ? aa : 0.f;
      ma |= (posa ? 1u : 0u) << e;
      float ab = accB[e] + bb;
      bool posb = ab > 0.f;
      hnB[e] = posb ? ab : 0.f;
      mb |= (posb ? 1u : 0u) << e;
    }
    *(unsigned short*)(masks + ((size_t)(l + 1) * NPTS + pA) * 32 + w * 2) =
        (unsigned short)ma;
    *(unsigned short*)(masks + ((size_t)(l + 1) * NPTS + pB) * 32 + w * 2) =
        (unsigned short)mb;
#pragma unroll
    for (int e = 0; e < 16; ++e) {
      hT[lane * SH + c0 + e] = hnA[e];
      hT[(64 + lane) * SH + c0 + e] = hnB[e];
    }
    __syncthreads();
  }

  // ---- p = h5 . Wout[:,1] + b_out[1]
  {
    float sA = 0.f, sB = 0.f;
#pragma unroll
    for (int e = 0; e < 16; ++e) {
      float wv = Wout[2 * (c0 + e) + 1];
      sA = fmaf(hT[lane * SH + c0 + e], wv, sA);
      sB = fmaf(hT[(64 + lane) * SH + c0 + e], wv, sB);
    }
    pscr[w][lane] = sA;
    pscr[w][64 + lane] = sB;
  }
  __syncthreads();
  if (tid < 128) {
    float s2 = 0.f;
#pragma unroll
    for (int g = 0; g < 16; ++g) s2 += pscr[g][tid];
    out[2 * NPTS + p0 + tid] = s2 + b_out[1];
  }
}

// ---------------------------------------------------------------- prep: Wh fp32 [l][k][n] -> fragment-major f16
// Wt2 flat index i = ((((l*4 + wn)*8 + s)*4 + nj)*64 + lane)*8 + j
// holds (f16)Wh[l][k][n] with k = s*32 + (lane>>4)*8 + j,
//                           n = wn*64 + nj*16 + (lane&15).
// A wave's B-fragment load (fixed l,wn,s,nj; lane 0..63; j 0..7) is then
// 64 x 16B = 1KB contiguous -> one fully-coalesced global_load_dwordx4.
__global__ void __launch_bounds__(256) prep_weights_kernel(
    const float* __restrict__ Wh, _Float16* __restrict__ Wt2) {
  int i = blockIdx.x * 256 + threadIdx.x;   // 0..262143
  int j = i & 7;
  int lane = (i >> 3) & 63;
  int nj = (i >> 9) & 3;
  int s = (i >> 11) & 7;
  int wn = (i >> 14) & 3;
  int l = i >> 16;
  int k = s * 32 + ((lane >> 4) << 3) + j;
  int n = wn * 64 + nj * 16 + (lane & 15);
  Wt2[i] = (_Float16)Wh[(size_t)l * 65536 + (size_t)k * 256 + n];
}

// ---------------------------------------------------------------- fused tangent chain (init + 4 layers + finalize)
// Block: 256 thr = 4 waves. 32 points -> 64 rows (0..31 x-tangent, 32..63 y).
// Tile M=64 x N=256; wave wn owns 64 rows x 64 cols. T lives in Apan (f16).
// v26: whole-layer B in registers (breg[8][4]), loaded from FRAGMENT-MAJOR
// Wt2 -> 32 fully-coalesced 1KB dwordx4 loads per wave per layer at layer
// top (compiler early-issues, counted vmcnt; latency hides under af+MFMA).
// No Bpan. LDS = Apan + smask = 38.9KB.
// mfma(bf, af, acc) OPERAND SWAP -> D[row = n-local quad*4+reg]
// [col = m-local l15]: lane holds 4 consecutive n for one row m ->
// write-back is 16 ds_write_b64. Finalize = one MFMA chain per wave.
// mfma_f32_16x16x32_f16: A[m=lane&15][k=quad*8+j], B[k=quad*8+j][n=lane&15],
//                        D[row=quad*4+reg][col=lane&15]  (verified layouts)
__global__ void __launch_bounds__(256, 2) tangent_fused_kernel(
    const float* __restrict__ Win,
    const _Float16* __restrict__ Wt2,         // fragment-major (see prep)
    const unsigned int* __restrict__ maskDw,  // [5][NPTS][8] dwords
    const float* __restrict__ Wout, float* __restrict__ out) {
  constexpr int SA = 264;   // A row stride (halves): 256 + 8 pad
  __shared__ alignas(16) _Float16 Apan[64 * SA];        // 33792 B
  __shared__ unsigned int smask[5 * 256];               // 5120 B

  const int tid = threadIdx.x;
  const int lane = tid & 63;
  const int wn = tid >> 6;          // wave = 64-col group
  const int l15 = lane & 15, quad = lane >> 4;
  const int p0 = blockIdx.x * 32;   // 32 points per block

  // ---- stage all 5 mask layers (32 pts x 8 dw each)
#pragma unroll
  for (int i = 0; i < 5; ++i)
    smask[i * 256 + tid] = maskDw[(size_t)i * NPTS * 8 + (size_t)p0 * 8 + tid];
  __syncthreads();

  // ---- init T1 into Apan: row<32 -> x-tangent (Win row 0), row>=32 -> y (row 1)
#pragma unroll
  for (int i = 0; i < 8; ++i) {
    int g = tid + 256 * i;          // 0..2047 col-groups of 8
    int row = g >> 5, cg = g & 31;
    int c0 = cg * 8, pt = row & 31, tg = row >> 5;
    unsigned dw = smask[pt * 8 + (c0 >> 5)];
    half8_t v;
#pragma unroll
    for (int e = 0; e < 8; ++e) {
      bool m = (dw >> ((cg & 3) * 8 + e)) & 1;
      v[e] = m ? (_Float16)Win[tg * 256 + c0 + e] : (_Float16)0.f;
    }
    *(half8_t*)&Apan[row * SA + c0] = v;
  }
  __syncthreads();                  // Apan init visible to all waves

  // ---- 4 layers: acc = A @ W_l (computed transposed), gate, back into Apan
  for (int l = 0; l < 4; ++l) {
    // fragment-major base for this (l, wn): fragments are 1KB apart,
    // this wave's lane slice is lane*16B within each.
    const _Float16* Bw = Wt2 + ((size_t)(l * 4 + wn) * 32 + 0) * 512 + (size_t)lane * 8;

    // ---- load ALL 32 B fragments for this layer: fully-coalesced 1KB each.
    half8_t breg[8][4];
#pragma unroll
    for (int s = 0; s < 8; ++s)
#pragma unroll
      for (int nj = 0; nj < 4; ++nj)
        breg[s][nj] = *(const half8_t*)(Bw + (size_t)(s * 4 + nj) * 512);

    floatx4 acc[4][4] = {};   // [mi][nj], element = D[n-local][m-local]
#pragma unroll
    for (int s = 0; s < 8; ++s) {     // s = kp*2+ks of v19: same k order
      half8_t af[4];
#pragma unroll
      for (int mi = 0; mi < 4; ++mi)
        af[mi] = *(const half8_t*)&Apan[(mi * 16 + l15) * SA + s * 32 + quad * 8];
      // SWAPPED operands: same products/order as v19 (bit-identical values),
      // transposed D layout (lane = one T-row m, 4 consecutive n per reg)
#pragma unroll
      for (int mi = 0; mi < 4; ++mi)
#pragma unroll
        for (int nj = 0; nj < 4; ++nj)
          acc[mi][nj] = __builtin_amdgcn_mfma_f32_16x16x32_f16(breg[s][nj], af[mi], acc[mi][nj], 0, 0, 0);
    }
    __syncthreads();          // all Apan reads of this layer done
    // gated write-back: lane (l15,quad) of tile (mi,nj) holds rows m=mi*16+l15,
    // cols C = wn*64 + nj*16 + quad*4 + r  -> one b64 per (mi,nj)
    const unsigned int* ml = &smask[(l + 1) * 256];
    uint2 mA = *(const uint2*)&ml[l15 * 8 + wn * 2];         // pt = l15
    uint2 mB = *(const uint2*)&ml[(16 + l15) * 8 + wn * 2];  // pt = 16+l15
#pragma unroll
    for (int mi = 0; mi < 4; ++mi) {
      uint2 md = (mi & 1) ? mB : mA;
      int m = mi * 16 + l15;
#pragma unroll
      for (int nj = 0; nj < 4; ++nj) {
        unsigned dw = (nj < 2) ? md.x : md.y;
        int bitbase = (nj & 1) * 16 + quad * 4;
        half4_t v;
#pragma unroll
        for (int r = 0; r < 4; ++r)
          v[r] = ((dw >> (bitbase + r)) & 1) ? (_Float16)acc[mi][nj][r]
                                             : (_Float16)0.f;
        *(half4_t*)&Apan[m * SA + wn * 64 + nj * 16 + quad * 4] = v;
      }
    }
    __syncthreads();
  }

  // ---- finalize: T5 @ Wout via one MFMA chain per wave (rows wn*16..+15)
  {
    floatx4 facc = {0.f, 0.f, 0.f, 0.f};
#pragma unroll
    for (int kc = 0; kc < 8; ++kc) {
      half8_t a = *(const half8_t*)&Apan[(wn * 16 + l15) * SA + kc * 32 + quad * 8];
      half8_t b;
#pragma unroll
      for (int j = 0; j < 8; ++j) {
        int k = kc * 32 + quad * 8 + j;
        b[j] = (l15 < 2) ? (_Float16)Wout[2 * k + l15] : (_Float16)0.f;
      }
      facc = __builtin_amdgcn_mfma_f32_16x16x32_f16(a, b, facc, 0, 0, 0);
    }
    // D[row=quad*4+r][col=l15]: global row = wn*16 + quad*4 + r; col 0 -> psi
    // derivative dot (u/v), col 1 -> p derivative dot (f/g)
    if (l15 < 2) {
#pragma unroll
      for (int r = 0; r < 4; ++r) {
        int row = wn * 16 + quad * 4 + r;
        int pt = p0 + (row & 31);
        float val = facc[r];
        if (l15 == 0) {
          if (row < 32) out[NPTS + pt] = -val;      // v = -psi_x
          else          out[pt] = val;              // u =  psi_y
        } else {
          if (row < 32) out[3 * NPTS + pt] = val;   // f = p_x
          else          out[4 * NPTS + pt] = val;   // g = p_y
        }
      }
    }
  }
}

// ---------------------------------------------------------------- launch
extern "C" void kernel_launch(void* const* d_in, const int* in_sizes, int n_in,
                              void* d_out, int out_size, void* d_ws, size_t ws_size,
                              hipStream_t stream) {
  const float* x = (const float*)d_in[0];
  const float* y = (const float*)d_in[1];
  const float* t = (const float*)d_in[2];
  const float* Win = (const float*)d_in[3];
  const float* b_in = (const float*)d_in[4];
  const float* Wh = (const float*)d_in[5];
  const float* b_h = (const float*)d_in[6];
  const float* Wout = (const float*)d_in[7];
  const float* b_out = (const float*)d_in[8];
  float* out = (float*)d_out;

  char* ws = (char*)d_ws;
  constexpr size_t MASK_SZ = (size_t)NPTS * 32;       // 2 MB per layer
  unsigned char* masks = (unsigned char*)ws;
  _Float16* Wt2 = (_Float16*)(ws + 5 * MASK_SZ);

  // weight transpose/cast/swizzle first (independent of fwd)
  prep_weights_kernel<<<1024, 256, 0, stream>>>(Wh, Wt2);

  // fp32 np-exact forward: masks L0..L4 + p
  fwd_fused_kernel<<<NPTS / 128, 1024, 0, stream>>>(
      x, y, t, Win, b_in, Wh, b_h, Wout, b_out, masks, out);

  // fused tangent chain: init + 4 MFMA layers + finalize (u,v,f,g)
  tangent_fused_kernel<<<NPTS / 32, 256, 0, stream>>>(
      Win, Wt2, (const unsigned int*)masks, Wout, out);
}